// Round 4
// baseline (100.343 us; speedup 1.0000x reference)
//
#include <hip/hip_runtime.h>
#include <math.h>

// Problem constants: B=2, H=W=64, C=64, N=4096, NUM_LEVELS=4, RADIUS=3 -> K=49
// out: (B, N, 4*49*64) f32 = 102,760,448 floats (411 MB)
// Pyramid in d_ws (f32):
//   L0: 2*64*64*64 @ 0        (524288 floats)   [normalized fmap2]
//   L1: 2*32*32*64 @ 524288   (131072)
//   L2: 2*16*16*64 @ 655360   ( 32768)
//   L3: 2* 8* 8*64 @ 688128   (  8192)
// float4 base per level l: (524288 - (524288>>2l))/3 = {0,131072,163840,172032}

typedef float f32x4 __attribute__((ext_vector_type(4)));

__global__ __launch_bounds__(256) void normalize_kernel(
    const float* __restrict__ in, float* __restrict__ out) {
  int gtid = blockIdx.x * 256 + threadIdx.x;
  int wave = gtid >> 6;          // pixel index, 0 .. 8191
  int lane = gtid & 63;          // channel
  float v = in[wave * 64 + lane];
  float ss = v * v;
  #pragma unroll
  for (int m = 32; m >= 1; m >>= 1) ss += __shfl_xor(ss, m);
  out[wave * 64 + lane] = v / (sqrtf(ss) + 1e-6f);
}

// ---- composed-filter pyramid (replaces the 3-kernel cascade) ----
// jax.image.resize 2x bilinear down: taps j=2i-1+t, base {.25,.75,.75,.25},
// out-of-range taps dropped and weights renormalized (per level).
__device__ __forceinline__ void taps4(int i, int S_in, float (&w)[4]) {
  float s = 0.f;
  #pragma unroll
  for (int t = 0; t < 4; t++) {
    int j = 2 * i - 1 + t;
    float bw = (t == 0 || t == 3) ? 0.25f : 0.75f;
    w[t] = (j >= 0 && j < S_in) ? bw : 0.f;
    s += w[t];
  }
  float inv = 1.f / s;
  #pragma unroll
  for (int t = 0; t < 4; t++) w[t] *= inv;
}

// Expand taps over level k (width N at offset jlo) into taps over the next
// finer level (width 2N+2 at offset 2*jlo-1). Validity vs that level's size.
template <int N>
__device__ __forceinline__ void expand_taps(int jlo, const float (&win)[N],
                                            int S_in, float (&wout)[2 * N + 2]) {
  #pragma unroll
  for (int t = 0; t < 2 * N + 2; t++) wout[t] = 0.f;
  #pragma unroll
  for (int t = 0; t < N; t++) {
    int i = jlo + t;
    float w4[4];
    float s = 0.f;
    #pragma unroll
    for (int u = 0; u < 4; u++) {
      int j = 2 * i - 1 + u;
      float bw = (u == 0 || u == 3) ? 0.25f : 0.75f;
      w4[u] = (j >= 0 && j < S_in) ? bw : 0.f;
      s += w4[u];
    }
    float inv = (win[t] != 0.f) ? win[t] / s : 0.f;  // guard 0/0 at edges
    #pragma unroll
    for (int u = 0; u < 4; u++) wout[2 * t + u] += w4[u] * inv;
  }
}

template <int NT>
__device__ __forceinline__ float gather2d(const float* __restrict__ L0n, int b,
                                          int ch, int ylo, int xlo,
                                          const float (&wy)[NT],
                                          const float (&wx)[NT]) {
  float acc = 0.f;
  #pragma unroll
  for (int a = 0; a < NT; a++) {
    if (wy[a] != 0.f) {              // wave-uniform branch (one px per wave)
      int jy = min(max(ylo + a, 0), 63);
      const float* row = L0n + (((b * 64 + jy) * 64) << 6) + ch;
      float racc = 0.f;
      #pragma unroll
      for (int t = 0; t < NT; t++) {
        int jx = min(max(xlo + t, 0), 63);
        racc += wx[t] * row[jx << 6];  // zero-weight taps load but add 0
      }
      acc += wy[a] * racc;
    }
  }
  return acc;
}

// One thread per pyramid element of L1..L3 (172032 total = 672 blocks).
// Lane = channel -> each wave handles one output pixel; coalesced 256B loads.
__global__ __launch_bounds__(256) void levels_kernel(
    const float* __restrict__ pyr_in, float* __restrict__ pyr_out) {
  int gtid = blockIdx.x * 256 + threadIdx.x;
  int ch = gtid & 63;
  int px = gtid >> 6;  // 0..2687:  L1 px<2048, L2 px<2560, L3 rest
  if (px < 2048) {
    int b = px >> 10, r = px & 1023, oy = r >> 5, ox = r & 31;
    float wy[4], wx[4];
    taps4(oy, 64, wy);
    taps4(ox, 64, wx);
    float v = gather2d<4>(pyr_in, b, ch, 2 * oy - 1, 2 * ox - 1, wy, wx);
    pyr_out[524288 + ((((b * 32 + oy) * 32 + ox)) << 6) + ch] = v;
  } else if (px < 2560) {
    int p = px - 2048, b = p >> 8, r = p & 255, oy = r >> 4, ox = r & 15;
    float t4[4], wy[10], wx[10];
    taps4(oy, 32, t4);
    expand_taps<4>(2 * oy - 1, t4, 64, wy);
    taps4(ox, 32, t4);
    expand_taps<4>(2 * ox - 1, t4, 64, wx);
    float v = gather2d<10>(pyr_in, b, ch, 4 * oy - 3, 4 * ox - 3, wy, wx);
    pyr_out[655360 + ((((b * 16 + oy) * 16 + ox)) << 6) + ch] = v;
  } else {
    int p = px - 2560, b = p >> 6, r = p & 63, oy = r >> 3, ox = r & 7;
    float t4[4], t10[10], wy[22], wx[22];
    taps4(oy, 16, t4);
    expand_taps<4>(2 * oy - 1, t4, 32, t10);
    expand_taps<10>(4 * oy - 3, t10, 64, wy);
    taps4(ox, 16, t4);
    expand_taps<4>(2 * ox - 1, t4, 32, t10);
    expand_taps<10>(4 * ox - 3, t10, 64, wx);
    float v = gather2d<22>(pyr_in, b, ch, 8 * oy - 7, 8 * ox - 7, wy, wx);
    pyr_out[688128 + ((((b * 8 + oy) * 8 + ox)) << 6) + ch] = v;
  }
}

// Register dx-walk sampler: one block per bn=(b,n), 448 threads.
// thread group g = l*7 + dyi (waves stay mostly within one level -> clustered
// reads and stores); c4 = t&15. Each thread emits 7 float4 outputs (dx walk),
// reusing the previous x1 texel pair as the next x0 pair.
__global__ __launch_bounds__(448, 4) void corr_sample_reg(
    const float* __restrict__ pyr, const float* __restrict__ coords,
    float* __restrict__ out) {
  unsigned bn = blockIdx.x;  // 0..8191
  unsigned b = bn >> 12;
  int t = threadIdx.x;
  int c4 = t & 15;
  int g = t >> 4;   // 0..27
  int l = g / 7;    // level (magic-mul)
  int dyi = g - l * 7;

  int Wl = 64 >> l;
  float sc = 1.0f / (float)(1 << l);  // exact power of two
  float fmx = (float)(Wl - 1);
  unsigned base4 = (524288u - (524288u >> (2 * l))) / 3u;

  float cx = coords[bn * 2 + 0];
  float cy = coords[bn * 2 + 1];
  float cxs = cx * sc, cys = cy * sc;

  // Reference quirk preserved: weights use CLIPPED x1/y1 -> exact zero at edge.
  float y = fminf(fmaxf(cys + (float)(dyi - 3), 0.f), fmx);
  int y0 = (int)floorf(y);
  int y1 = min(y0 + 1, Wl - 1);
  float wy0 = (float)y1 - y;
  float wy1 = y - (float)y0;

  const float4* p4 = (const float4*)pyr;
  unsigned pixb = (unsigned)(b * Wl * Wl);
  unsigned r0 = base4 + ((pixb + (unsigned)(y0 * Wl)) << 4) + (unsigned)c4;
  unsigned r1 = base4 + ((pixb + (unsigned)(y1 * Wl)) << 4) + (unsigned)c4;

  unsigned ob = bn * 3136u + (unsigned)l * 784u + ((unsigned)(dyi * 7) << 4) +
                (unsigned)c4;
  f32x4* o4 = (f32x4*)out;

  int px = -1;  // x1 >= 1 always, so -1 never falsely matches
  float4 a0 = make_float4(0.f, 0.f, 0.f, 0.f), a1 = a0;
  #pragma unroll
  for (int dxi = 0; dxi < 7; ++dxi) {
    float x = fminf(fmaxf(cxs + (float)(dxi - 3), 0.f), fmx);
    int x0 = (int)floorf(x);
    int x1 = min(x0 + 1, Wl - 1);
    float wx0 = (float)x1 - x;
    float wx1 = x - (float)x0;

    float4 b0, b1;
    if (x0 == px) {
      b0 = a0; b1 = a1;
    } else {
      b0 = p4[r0 + ((unsigned)x0 << 4)];
      b1 = p4[r1 + ((unsigned)x0 << 4)];
    }
    a0 = p4[r0 + ((unsigned)x1 << 4)];
    a1 = p4[r1 + ((unsigned)x1 << 4)];
    px = x1;

    f32x4 r;
    r.x = wx0 * (wy0 * b0.x + wy1 * b1.x) + wx1 * (wy0 * a0.x + wy1 * a1.x);
    r.y = wx0 * (wy0 * b0.y + wy1 * b1.y) + wx1 * (wy0 * a0.y + wy1 * a1.y);
    r.z = wx0 * (wy0 * b0.z + wy1 * b1.z) + wx1 * (wy0 * a0.z + wy1 * a1.z);
    r.w = wx0 * (wy0 * b0.w + wy1 * b1.w) + wx1 * (wy0 * a0.w + wy1 * a1.w);
    // Output is a pure 411 MB stream, never re-read: bypass L2 allocation.
    __builtin_nontemporal_store(r, o4 + ob + (unsigned)(dxi << 4));
  }
}

extern "C" void kernel_launch(void* const* d_in, const int* in_sizes, int n_in,
                              void* d_out, int out_size, void* d_ws, size_t ws_size,
                              hipStream_t stream) {
  // d_in[0] = fmap1 (normalized then discarded by the reference)
  const float* fmap2 = (const float*)d_in[1];
  const float* coords = (const float*)d_in[2];
  float* out = (float*)d_out;
  float* pyr = (float*)d_ws;

  normalize_kernel<<<2048, 256, 0, stream>>>(fmap2, pyr);
  // L1+L2+L3 directly from normalized L0 via composed filters (one kernel).
  levels_kernel<<<672, 256, 0, stream>>>(pyr, pyr);
  // One block per (b,n): 8192 blocks x 448 threads; no LDS, no barriers.
  corr_sample_reg<<<8192, 448, 0, stream>>>(pyr, coords, out);
}

// Round 5
// 94.674 us; speedup vs baseline: 1.0599x; 1.0599x over previous
//
#include <hip/hip_runtime.h>
#include <math.h>

// Problem constants: B=2, H=W=64, C=64, N=4096, NUM_LEVELS=4, RADIUS=3 -> K=49
// out: (B, N, 4*49*64) f32 = 102,760,448 floats (411 MB)
// Pyramid in d_ws (f32):
//   L0: 2*64*64*64 @ 0        (524288 floats)   [normalized fmap2]
//   L1: 2*32*32*64 @ 524288   (131072)
//   L2: 2*16*16*64 @ 655360   ( 32768)
//   L3: 2* 8* 8*64 @ 688128   (  8192)
// float4 base per level l: (524288 - (524288>>2l))/3 = {0,131072,163840,172032}

typedef float f32x4 __attribute__((ext_vector_type(4)));

__global__ __launch_bounds__(256) void normalize_kernel(
    const float* __restrict__ in, float* __restrict__ out) {
  int gtid = blockIdx.x * 256 + threadIdx.x;
  int wave = gtid >> 6;          // pixel index, 0 .. 8191
  int lane = gtid & 63;          // channel
  float v = in[wave * 64 + lane];
  float ss = v * v;
  #pragma unroll
  for (int m = 32; m >= 1; m >>= 1) ss += __shfl_xor(ss, m);
  out[wave * 64 + lane] = v / (sqrtf(ss) + 1e-6f);
}

// ---- composed-filter pyramid (replaces the 3-kernel cascade) ----
// jax.image.resize 2x bilinear down: taps j=2i-1+t, base {.25,.75,.75,.25},
// out-of-range taps dropped and weights renormalized (per level).
__device__ __forceinline__ void taps4(int i, int S_in, float (&w)[4]) {
  float s = 0.f;
  #pragma unroll
  for (int t = 0; t < 4; t++) {
    int j = 2 * i - 1 + t;
    float bw = (t == 0 || t == 3) ? 0.25f : 0.75f;
    w[t] = (j >= 0 && j < S_in) ? bw : 0.f;
    s += w[t];
  }
  float inv = 1.f / s;
  #pragma unroll
  for (int t = 0; t < 4; t++) w[t] *= inv;
}

// Expand taps over level k (width N at offset jlo) into taps over the next
// finer level (width 2N+2 at offset 2*jlo-1). Validity vs that level's size.
template <int N>
__device__ __forceinline__ void expand_taps(int jlo, const float (&win)[N],
                                            int S_in, float (&wout)[2 * N + 2]) {
  #pragma unroll
  for (int t = 0; t < 2 * N + 2; t++) wout[t] = 0.f;
  #pragma unroll
  for (int t = 0; t < N; t++) {
    int i = jlo + t;
    float w4[4];
    float s = 0.f;
    #pragma unroll
    for (int u = 0; u < 4; u++) {
      int j = 2 * i - 1 + u;
      float bw = (u == 0 || u == 3) ? 0.25f : 0.75f;
      w4[u] = (j >= 0 && j < S_in) ? bw : 0.f;
      s += w4[u];
    }
    float inv = (win[t] != 0.f) ? win[t] / s : 0.f;  // guard 0/0 at edges
    #pragma unroll
    for (int u = 0; u < 4; u++) wout[2 * t + u] += w4[u] * inv;
  }
}

template <int NT>
__device__ __forceinline__ float gather2d(const float* __restrict__ L0n, int b,
                                          int ch, int ylo, int xlo,
                                          const float (&wy)[NT],
                                          const float (&wx)[NT]) {
  float acc = 0.f;
  #pragma unroll
  for (int a = 0; a < NT; a++) {
    if (wy[a] != 0.f) {              // wave-uniform branch (one px per wave)
      int jy = min(max(ylo + a, 0), 63);
      const float* row = L0n + (((b * 64 + jy) * 64) << 6) + ch;
      float racc = 0.f;
      #pragma unroll
      for (int t = 0; t < NT; t++) {
        int jx = min(max(xlo + t, 0), 63);
        racc += wx[t] * row[jx << 6];  // zero-weight taps load but add 0
      }
      acc += wy[a] * racc;
    }
  }
  return acc;
}

// One thread per pyramid element of L1..L3 (172032 total = 672 blocks).
// Lane = channel -> each wave handles one output pixel; coalesced 256B loads.
__global__ __launch_bounds__(256) void levels_kernel(
    const float* __restrict__ pyr_in, float* __restrict__ pyr_out) {
  int gtid = blockIdx.x * 256 + threadIdx.x;
  int ch = gtid & 63;
  int px = gtid >> 6;  // 0..2687:  L1 px<2048, L2 px<2560, L3 rest
  if (px < 2048) {
    int b = px >> 10, r = px & 1023, oy = r >> 5, ox = r & 31;
    float wy[4], wx[4];
    taps4(oy, 64, wy);
    taps4(ox, 64, wx);
    float v = gather2d<4>(pyr_in, b, ch, 2 * oy - 1, 2 * ox - 1, wy, wx);
    pyr_out[524288 + ((((b * 32 + oy) * 32 + ox)) << 6) + ch] = v;
  } else if (px < 2560) {
    int p = px - 2048, b = p >> 8, r = p & 255, oy = r >> 4, ox = r & 15;
    float t4[4], wy[10], wx[10];
    taps4(oy, 32, t4);
    expand_taps<4>(2 * oy - 1, t4, 64, wy);
    taps4(ox, 32, t4);
    expand_taps<4>(2 * ox - 1, t4, 64, wx);
    float v = gather2d<10>(pyr_in, b, ch, 4 * oy - 3, 4 * ox - 3, wy, wx);
    pyr_out[655360 + ((((b * 16 + oy) * 16 + ox)) << 6) + ch] = v;
  } else {
    int p = px - 2560, b = p >> 6, r = p & 63, oy = r >> 3, ox = r & 7;
    float t4[4], t10[10], wy[22], wx[22];
    taps4(oy, 16, t4);
    expand_taps<4>(2 * oy - 1, t4, 32, t10);
    expand_taps<10>(4 * oy - 3, t10, 64, wy);
    taps4(ox, 16, t4);
    expand_taps<4>(2 * ox - 1, t4, 32, t10);
    expand_taps<10>(4 * ox - 3, t10, 64, wx);
    float v = gather2d<22>(pyr_in, b, ch, 8 * oy - 7, 8 * ox - 7, wy, wx);
    pyr_out[688128 + ((((b * 8 + oy) * 8 + ox)) << 6) + ch] = v;
  }
}

// Register dx-walk sampler: one block per bn=(b,n), 448 threads.
// thread group g = l*7 + dyi (waves stay mostly within one level -> clustered
// reads and stores); c4 = t&15. Each thread emits 7 float4 outputs (dx walk),
// reusing the previous x1 texel pair as the next x0 pair.
__global__ __launch_bounds__(448, 4) void corr_sample_reg(
    const float* __restrict__ pyr, const float* __restrict__ coords,
    float* __restrict__ out) {
  unsigned bn = blockIdx.x;  // 0..8191
  unsigned b = bn >> 12;
  int t = threadIdx.x;
  int c4 = t & 15;
  int g = t >> 4;   // 0..27
  int l = g / 7;    // level (magic-mul)
  int dyi = g - l * 7;

  int Wl = 64 >> l;
  float sc = 1.0f / (float)(1 << l);  // exact power of two
  float fmx = (float)(Wl - 1);
  unsigned base4 = (524288u - (524288u >> (2 * l))) / 3u;

  float cx = coords[bn * 2 + 0];
  float cy = coords[bn * 2 + 1];
  float cxs = cx * sc, cys = cy * sc;

  // Reference quirk preserved: weights use CLIPPED x1/y1 -> exact zero at edge.
  float y = fminf(fmaxf(cys + (float)(dyi - 3), 0.f), fmx);
  int y0 = (int)floorf(y);
  int y1 = min(y0 + 1, Wl - 1);
  float wy0 = (float)y1 - y;
  float wy1 = y - (float)y0;

  const float4* p4 = (const float4*)pyr;
  unsigned pixb = (unsigned)(b * Wl * Wl);
  unsigned r0 = base4 + ((pixb + (unsigned)(y0 * Wl)) << 4) + (unsigned)c4;
  unsigned r1 = base4 + ((pixb + (unsigned)(y1 * Wl)) << 4) + (unsigned)c4;

  unsigned ob = bn * 3136u + (unsigned)l * 784u + ((unsigned)(dyi * 7) << 4) +
                (unsigned)c4;
  float4* o4 = (float4*)out;

  int px = -1;  // x1 >= 1 always, so -1 never falsely matches
  float4 a0 = make_float4(0.f, 0.f, 0.f, 0.f), a1 = a0;
  #pragma unroll
  for (int dxi = 0; dxi < 7; ++dxi) {
    float x = fminf(fmaxf(cxs + (float)(dxi - 3), 0.f), fmx);
    int x0 = (int)floorf(x);
    int x1 = min(x0 + 1, Wl - 1);
    float wx0 = (float)x1 - x;
    float wx1 = x - (float)x0;

    float4 b0, b1;
    if (x0 == px) {
      b0 = a0; b1 = a1;
    } else {
      b0 = p4[r0 + ((unsigned)x0 << 4)];
      b1 = p4[r1 + ((unsigned)x0 << 4)];
    }
    a0 = p4[r0 + ((unsigned)x1 << 4)];
    a1 = p4[r1 + ((unsigned)x1 << 4)];
    px = x1;

    float4 r;
    r.x = wx0 * (wy0 * b0.x + wy1 * b1.x) + wx1 * (wy0 * a0.x + wy1 * a1.x);
    r.y = wx0 * (wy0 * b0.y + wy1 * b1.y) + wx1 * (wy0 * a0.y + wy1 * a1.y);
    r.z = wx0 * (wy0 * b0.z + wy1 * b1.z) + wx1 * (wy0 * a0.z + wy1 * a1.z);
    r.w = wx0 * (wy0 * b0.w + wy1 * b1.w) + wx1 * (wy0 * a0.w + wy1 * a1.w);
    o4[ob + (unsigned)(dxi << 4)] = r;   // regular store (NT removed: A/B)
  }
}

extern "C" void kernel_launch(void* const* d_in, const int* in_sizes, int n_in,
                              void* d_out, int out_size, void* d_ws, size_t ws_size,
                              hipStream_t stream) {
  // d_in[0] = fmap1 (normalized then discarded by the reference)
  const float* fmap2 = (const float*)d_in[1];
  const float* coords = (const float*)d_in[2];
  float* out = (float*)d_out;
  float* pyr = (float*)d_ws;

  normalize_kernel<<<2048, 256, 0, stream>>>(fmap2, pyr);
  // L1+L2+L3 directly from normalized L0 via composed filters (one kernel).
  levels_kernel<<<672, 256, 0, stream>>>(pyr, pyr);
  // One block per (b,n): 8192 blocks x 448 threads; no LDS, no barriers.
  corr_sample_reg<<<8192, 448, 0, stream>>>(pyr, coords, out);
}

// Round 6
// 87.742 us; speedup vs baseline: 1.1436x; 1.0790x over previous
//
#include <hip/hip_runtime.h>
#include <math.h>

// Problem constants: B=2, H=W=64, C=64, N=4096, NUM_LEVELS=4, RADIUS=3 -> K=49
// out: (B, N, 4*49*64) f32 = 102,760,448 floats (411 MB)
// Pyramid in d_ws (f32):
//   L0: 2*64*64*64 @ 0        (524288 floats)   [normalized fmap2]
//   L1: 2*32*32*64 @ 524288   (131072)
//   L2: 2*16*16*64 @ 655360   ( 32768)
//   L3: 2* 8* 8*64 @ 688128   (  8192)
// float4 base per level l: (524288 - (524288>>2l))/3 = {0,131072,163840,172032}

__global__ __launch_bounds__(256) void normalize_kernel(
    const float* __restrict__ in, float* __restrict__ out) {
  int gtid = blockIdx.x * 256 + threadIdx.x;
  int wave = gtid >> 6;          // pixel index, 0 .. 8191
  int lane = gtid & 63;          // channel
  float v = in[wave * 64 + lane];
  float ss = v * v;
  #pragma unroll
  for (int m = 32; m >= 1; m >>= 1) ss += __shfl_xor(ss, m);
  out[wave * 64 + lane] = v / (sqrtf(ss) + 1e-6f);
}

// 2x antialiased bilinear downsample (jax.image.resize semantics):
// output i <- input taps {2i-1..2i+2}, base weights {.25,.75,.75,.25},
// out-of-range taps dropped, weights renormalized.
__global__ __launch_bounds__(256) void downsample_kernel(
    const float* __restrict__ in, float* __restrict__ out, int Si) {
  int So = Si >> 1;
  int gtid = blockIdx.x * 256 + threadIdx.x;
  int wave = gtid >> 6;
  int lane = gtid & 63;
  int ox = wave % So;
  int t  = wave / So;
  int oy = t % So;
  int b  = t / So;

  int xs[4], ys[4];
  float wx[4], wy[4];
  float bw[4] = {0.25f, 0.75f, 0.75f, 0.25f};
  float sx = 0.f, sy = 0.f;
  #pragma unroll
  for (int tt = 0; tt < 4; tt++) {
    int jx = 2 * ox - 1 + tt;
    bool vx = (jx >= 0) && (jx < Si);
    xs[tt] = vx ? jx : 0;
    wx[tt] = vx ? bw[tt] : 0.f;
    sx += wx[tt];
    int jy = 2 * oy - 1 + tt;
    bool vy = (jy >= 0) && (jy < Si);
    ys[tt] = vy ? jy : 0;
    wy[tt] = vy ? bw[tt] : 0.f;
    sy += wy[tt];
  }
  float ix = 1.f / sx, iy = 1.f / sy;
  #pragma unroll
  for (int tt = 0; tt < 4; tt++) { wx[tt] *= ix; wy[tt] *= iy; }

  float acc = 0.f;
  #pragma unroll
  for (int a = 0; a < 4; a++) {
    const float* rp = in + ((long)(b * Si + ys[a]) * Si) * 64 + lane;
    float row = 0.f;
    #pragma unroll
    for (int tt = 0; tt < 4; tt++) row += wx[tt] * rp[xs[tt] * 64];
    acc += wy[a] * row;
  }
  out[((long)(b * So + oy) * So + ox) * 64 + lane] = acc;
}

// Register dx-walk sampler: one block per bn=(b,n), 448 threads.
// thread group g = l*7 + dyi (waves stay within one level -> clustered reads
// and stores); c4 = t&15. Each thread emits 7 float4 outputs (dx walk),
// reusing the previous x1 texel pair as the next x0 pair.
__global__ __launch_bounds__(448, 4) void corr_sample_reg(
    const float* __restrict__ pyr, const float* __restrict__ coords,
    float* __restrict__ out) {
  unsigned bn = blockIdx.x;  // 0..8191
  unsigned b = bn >> 12;
  int t = threadIdx.x;
  int c4 = t & 15;
  int g = t >> 4;   // 0..27
  int l = g / 7;    // level (magic-mul)
  int dyi = g - l * 7;

  int Wl = 64 >> l;
  float sc = 1.0f / (float)(1 << l);  // exact power of two
  float fmx = (float)(Wl - 1);
  unsigned base4 = (524288u - (524288u >> (2 * l))) / 3u;

  float cx = coords[bn * 2 + 0];
  float cy = coords[bn * 2 + 1];
  float cxs = cx * sc, cys = cy * sc;

  // Reference quirk preserved: weights use CLIPPED x1/y1 -> exact zero at edge.
  float y = fminf(fmaxf(cys + (float)(dyi - 3), 0.f), fmx);
  int y0 = (int)floorf(y);
  int y1 = min(y0 + 1, Wl - 1);
  float wy0 = (float)y1 - y;
  float wy1 = y - (float)y0;

  const float4* p4 = (const float4*)pyr;
  unsigned pixb = (unsigned)(b * Wl * Wl);
  unsigned r0 = base4 + ((pixb + (unsigned)(y0 * Wl)) << 4) + (unsigned)c4;
  unsigned r1 = base4 + ((pixb + (unsigned)(y1 * Wl)) << 4) + (unsigned)c4;

  unsigned ob = bn * 3136u + (unsigned)l * 784u + ((unsigned)(dyi * 7) << 4) +
                (unsigned)c4;
  float4* o4 = (float4*)out;

  int px = -1;  // x1 >= 1 always, so -1 never falsely matches
  float4 a0 = make_float4(0.f, 0.f, 0.f, 0.f), a1 = a0;
  #pragma unroll
  for (int dxi = 0; dxi < 7; ++dxi) {
    float x = fminf(fmaxf(cxs + (float)(dxi - 3), 0.f), fmx);
    int x0 = (int)floorf(x);
    int x1 = min(x0 + 1, Wl - 1);
    float wx0 = (float)x1 - x;
    float wx1 = x - (float)x0;

    float4 b0, b1;
    if (x0 == px) {
      b0 = a0; b1 = a1;
    } else {
      b0 = p4[r0 + ((unsigned)x0 << 4)];
      b1 = p4[r1 + ((unsigned)x0 << 4)];
    }
    a0 = p4[r0 + ((unsigned)x1 << 4)];
    a1 = p4[r1 + ((unsigned)x1 << 4)];
    px = x1;

    float4 r;
    r.x = wx0 * (wy0 * b0.x + wy1 * b1.x) + wx1 * (wy0 * a0.x + wy1 * a1.x);
    r.y = wx0 * (wy0 * b0.y + wy1 * b1.y) + wx1 * (wy0 * a0.y + wy1 * a1.y);
    r.z = wx0 * (wy0 * b0.z + wy1 * b1.z) + wx1 * (wy0 * a0.z + wy1 * a1.z);
    r.w = wx0 * (wy0 * b0.w + wy1 * b1.w) + wx1 * (wy0 * a0.w + wy1 * a1.w);
    o4[ob + (unsigned)(dxi << 4)] = r;
  }
}

extern "C" void kernel_launch(void* const* d_in, const int* in_sizes, int n_in,
                              void* d_out, int out_size, void* d_ws, size_t ws_size,
                              hipStream_t stream) {
  // d_in[0] = fmap1 (normalized then discarded by the reference)
  const float* fmap2 = (const float*)d_in[1];
  const float* coords = (const float*)d_in[2];
  float* out = (float*)d_out;
  float* pyr = (float*)d_ws;

  normalize_kernel<<<2048, 256, 0, stream>>>(fmap2, pyr);
  downsample_kernel<<<512, 256, 0, stream>>>(pyr,          pyr + 524288, 64);
  downsample_kernel<<<128, 256, 0, stream>>>(pyr + 524288, pyr + 655360, 32);
  downsample_kernel<<< 32, 256, 0, stream>>>(pyr + 655360, pyr + 688128, 16);
  // One block per (b,n): 8192 blocks x 448 threads; no LDS, no barriers.
  corr_sample_reg<<<8192, 448, 0, stream>>>(pyr, coords, out);
}